// Round 8
// baseline (1060.092 us; speedup 1.0000x reference)
//
#include <hip/hip_runtime.h>
#include <stdint.h>

#define N_NODES 4096
#define NGRAPH 8
#define NPTS 512
#define KNN 64
#define EPSN 1e-5f

typedef _Float16 f16x8 __attribute__((ext_vector_type(8)));
typedef float f32x4 __attribute__((ext_vector_type(4)));

__device__ __forceinline__ unsigned short f2h(float f) {
    _Float16 h = (_Float16)f;   // RNE, v_cvt_f16_f32
    union { _Float16 h; unsigned short u; } cv; cv.h = h;
    return cv.u;
}

// ---------------- kNN: one block per dst point, bitonic sort of 512 (d2,idx) keys ----------------
__global__ __launch_bounds__(512) void knn_kernel(const float* __restrict__ pos, int* __restrict__ knn_out) {
#pragma clang fp contract(off)
    __shared__ float px[NPTS], py[NPTS], pz[NPTS];
    __shared__ unsigned long long keys[NPTS];
    int b = blockIdx.x >> 9;
    int il = blockIdx.x & (NPTS - 1);
    int tid = threadIdx.x;
    {
        int base = (b * NPTS + tid) * 3;
        px[tid] = pos[base]; py[tid] = pos[base + 1]; pz[tid] = pos[base + 2];
    }
    __syncthreads();
    float xi = px[il], yi = py[il], zi = pz[il];
    {
        float dx = px[tid] - xi, dy = py[tid] - yi, dz = pz[tid] - zi;
        float d2 = dx * dx;
        d2 = d2 + dy * dy;
        d2 = d2 + dz * dz;
        keys[tid] = (((unsigned long long)__float_as_uint(d2)) << 32) | (unsigned)tid;
    }
    for (int k2 = 2; k2 <= NPTS; k2 <<= 1) {
        for (int j = k2 >> 1; j > 0; j >>= 1) {
            __syncthreads();
            int ixj = tid ^ j;
            if (ixj > tid) {
                unsigned long long a = keys[tid], c = keys[ixj];
                bool up = ((tid & k2) == 0);
                if ((a > c) == up) { keys[tid] = c; keys[ixj] = a; }
            }
        }
    }
    __syncthreads();
    if (tid < KNN) {
        int j = (int)(keys[tid] & 0xffffffffu);
        knn_out[(b * NPTS + il) * KNN + tid] = b * NPTS + j;
    }
}

// ---------------- GraphNorm fused: stats + apply (+optional relu) ----------------
__global__ __launch_bounds__(256) void gn_fused(const float* __restrict__ x, const float* __restrict__ ms,
                                                const float* __restrict__ w, const float* __restrict__ bn,
                                                int C, float* __restrict__ out, int relu) {
    __shared__ float r1[4][64], r2[4][64];
    __shared__ float As[64], Ss[64];
    int b = blockIdx.y;
    int cl = threadIdx.x & 63;
    int c = blockIdx.x * 64 + cl;
    int part = threadIdx.x >> 6;
    float s1 = 0.f, s2 = 0.f;
    if (c < C) {
        for (int n = part; n < NPTS; n += 4) {
            float v = x[(size_t)(b * NPTS + n) * C + c];
            s1 += v; s2 += v * v;
        }
    }
    r1[part][cl] = s1;
    r2[part][cl] = s2;
    __syncthreads();
    if (part == 0 && c < C) {
        s1 = r1[0][cl] + r1[1][cl] + r1[2][cl] + r1[3][cl];
        s2 = r2[0][cl] + r2[1][cl] + r2[2][cl] + r2[3][cl];
        float mean = s1 * (1.f / NPTS);
        float ex2 = s2 * (1.f / NPTS);
        float a = mean * ms[c];
        float var = ex2 - 2.f * a * mean + a * a;   // E[(x - mean*ms)^2]
        As[cl] = a;
        Ss[cl] = w[c] / sqrtf(var + EPSN);
    }
    __syncthreads();
    if (c < C) {
        float a = As[cl], sf = Ss[cl], bb = bn[c];
        for (int n = part; n < NPTS; n += 4) {
            size_t idx = (size_t)(b * NPTS + n) * C + c;
            float v = (x[idx] - a) * sf + bb;
            if (relu) v = fmaxf(v, 0.f);
            out[idx] = v;
        }
    }
}

// ---------------- Per-node MLP1 v2: each block computes 16 rows x ALL C cols ----------------
template<int CIN, int C>
__global__ __launch_bounds__(C) void node_kernel(const float* __restrict__ h, const float* __restrict__ pos,
                                                 const float* __restrict__ w1, const float* __restrict__ b1,
                                                 float* __restrict__ U, float* __restrict__ P) {
    constexpr int ROWS = 16;
    constexpr int KC = 64;
    constexpr int LDH = KC + 4;
    __shared__ float hs[ROWS][LDH];   // 4352 B
    const int c = threadIdx.x;
    const int n0 = blockIdx.x * ROWS;
    float acc[ROWS];
    #pragma unroll
    for (int r = 0; r < ROWS; ++r) acc[r] = 0.f;
    constexpr int NCHUNK = (CIN + KC - 1) / KC;
    #pragma unroll 1
    for (int s = 0; s < NCHUNK; ++s) {
        const int k0 = s * KC;
        const int kc = (CIN - k0 < KC) ? (CIN - k0) : KC;
        __syncthreads();
        for (int idx = c; idx < ROWS * kc; idx += C) {
            int r = idx / kc, k = idx - r * kc;
            hs[r][k] = h[(size_t)(n0 + r) * CIN + k0 + k];
        }
        __syncthreads();
        int k = 0;
        for (; k + 4 <= kc; k += 4) {
            float w0 = w1[(size_t)(k0 + k) * C + c];
            float w1v = w1[(size_t)(k0 + k + 1) * C + c];
            float w2v = w1[(size_t)(k0 + k + 2) * C + c];
            float w3v = w1[(size_t)(k0 + k + 3) * C + c];
            #pragma unroll
            for (int r = 0; r < ROWS; ++r) {
                f32x4 hv = *(const f32x4*)&hs[r][k];
                acc[r] = fmaf(hv[0], w0, acc[r]);
                acc[r] = fmaf(hv[1], w1v, acc[r]);
                acc[r] = fmaf(hv[2], w2v, acc[r]);
                acc[r] = fmaf(hv[3], w3v, acc[r]);
            }
        }
        for (; k < kc; ++k) {
            float wv = w1[(size_t)(k0 + k) * C + c];
            #pragma unroll
            for (int r = 0; r < ROWS; ++r)
                acc[r] = fmaf(hs[r][k], wv, acc[r]);
        }
    }
    float pacc[ROWS];
    #pragma unroll
    for (int r = 0; r < ROWS; ++r) pacc[r] = 0.f;
    #pragma unroll
    for (int e = 0; e < 3; ++e) {
        float wv = w1[(size_t)(CIN + e) * C + c];
        #pragma unroll
        for (int r = 0; r < ROWS; ++r)
            pacc[r] = fmaf(pos[(n0 + r) * 3 + e], wv, pacc[r]);
    }
    float bv = b1[c];
    #pragma unroll
    for (int r = 0; r < ROWS; ++r) {
        U[(size_t)(n0 + r) * C + c] = acc[r] + pacc[r] + bv;
        P[(size_t)(n0 + r) * C + c] = pacc[r];
    }
}

// ---------------- w2 (C x C fp32, [k][n]) -> blocked fp16 layout ----------------
// dst[(ctg*(C/32)+s32)*512 + quad*128 + m*8 + j]  where n = ctg*16+m, k = s32*32+quad*8+j
__global__ void w2tt_kernel(const float* __restrict__ w2, unsigned short* __restrict__ w2t, int C) {
    int idx = blockIdx.x * 256 + threadIdx.x;
    if (idx >= C * C) return;
    int k = idx / C, n = idx % C;
    int dst = ((n >> 4) * (C / 32) + (k >> 5)) * 512 + ((k >> 3) & 3) * 128 + (n & 15) * 8 + (k & 7);
    w2t[dst] = f2h(w2[idx]);
}

// ---------------- Edge MLP2 + scatter-max ----------------
// One block per dst node (XCD-graph-swizzled). W waves; wave w owns cols [w*NCT*16,(w+1)*NCT*16).
// BK=32 per barrier iter; A-prefetch (U/P regs) + B-prefetch (w2t regs, crosses barrier) + LDS dbuf.
template<int C, int W>
__global__ __launch_bounds__(W * 64, 4) void edge_kernel(const float* __restrict__ U, const float* __restrict__ P,
                                                         const int* __restrict__ knn, const unsigned short* __restrict__ w2t,
                                                         const float* __restrict__ b2, float* __restrict__ Y) {
    constexpr int NCT = C / (W * 16);    // col tiles per wave
    constexpr int EPT = 32 / W;          // staging cols per thread (8 or 4)
    constexpr int S = C / 32;            // barrier iterations (one k32 each)
    constexpr int LD = 40;               // LDS row stride (halves)
    __shared__ unsigned short Tb[2][64 * LD];
    __shared__ int jn[64];
    const int bid = blockIdx.x;
    const int i = ((bid & 7) << 9) | (bid >> 3);   // XCD = bid%8 = graph(i): gather stays in one L2
    const int tid = threadIdx.x;
    const int wave = tid >> 6, lane = tid & 63, m = lane & 15, quad = lane >> 4;
    const int cw = wave * (NCT * 16);
    if (tid < 64) jn[tid] = knn[(size_t)i * KNN + tid];
    f32x4 acc[4][NCT];
    f32x4 zero = {0.f, 0.f, 0.f, 0.f};
    #pragma unroll
    for (int rt = 0; rt < 4; ++rt)
        #pragma unroll
        for (int ct = 0; ct < NCT; ++ct)
            acc[rt][ct] = zero;
    const int rr = tid / W;              // staging row 0..63
    const int c0 = (tid % W) * EPT;      // staging col base within k32 window
    __syncthreads();                     // jn visible
    const float* upr = U + (size_t)jn[rr] * C + c0;
    const float* ppr = P + (size_t)i * C + c0;
    const unsigned short* wbase = w2t + quad * 128 + m * 8;
    float4 uf[EPT / 4], pf[EPT / 4];
    #pragma unroll
    for (int g = 0; g < EPT / 4; ++g) {
        uf[g] = *(const float4*)(upr + g * 4);
        pf[g] = *(const float4*)(ppr + g * 4);
    }
    f16x8 bb[NCT], bn[NCT];
    #pragma unroll
    for (int ct = 0; ct < NCT; ++ct)
        bb[ct] = *(const f16x8*)(wbase + (size_t)(((cw >> 4) + ct) * S) * 512);
    #pragma unroll 2
    for (int s = 0; s < S; ++s) {
        unsigned short* tb = Tb[s & 1];
        if constexpr (EPT == 8) {
            uint4 pk;
            pk.x = (unsigned)f2h(fmaxf(uf[0].x - pf[0].x, 0.f)) | ((unsigned)f2h(fmaxf(uf[0].y - pf[0].y, 0.f)) << 16);
            pk.y = (unsigned)f2h(fmaxf(uf[0].z - pf[0].z, 0.f)) | ((unsigned)f2h(fmaxf(uf[0].w - pf[0].w, 0.f)) << 16);
            pk.z = (unsigned)f2h(fmaxf(uf[1].x - pf[1].x, 0.f)) | ((unsigned)f2h(fmaxf(uf[1].y - pf[1].y, 0.f)) << 16);
            pk.w = (unsigned)f2h(fmaxf(uf[1].z - pf[1].z, 0.f)) | ((unsigned)f2h(fmaxf(uf[1].w - pf[1].w, 0.f)) << 16);
            *(uint4*)&tb[rr * LD + c0] = pk;
        } else {
            uint2 pk;
            pk.x = (unsigned)f2h(fmaxf(uf[0].x - pf[0].x, 0.f)) | ((unsigned)f2h(fmaxf(uf[0].y - pf[0].y, 0.f)) << 16);
            pk.y = (unsigned)f2h(fmaxf(uf[0].z - pf[0].z, 0.f)) | ((unsigned)f2h(fmaxf(uf[0].w - pf[0].w, 0.f)) << 16);
            *(uint2*)&tb[rr * LD + c0] = pk;
        }
        if (s + 1 < S) {                 // A-prefetch next k32 window
            #pragma unroll
            for (int g = 0; g < EPT / 4; ++g) {
                uf[g] = *(const float4*)(upr + (s + 1) * 32 + g * 4);
                pf[g] = *(const float4*)(ppr + (s + 1) * 32 + g * 4);
            }
            #pragma unroll
            for (int ct = 0; ct < NCT; ++ct)   // B-prefetch next k32 (read-only; crosses barrier)
                bn[ct] = *(const f16x8*)(wbase + (size_t)(((cw >> 4) + ct) * S + s + 1) * 512);
        }
        __syncthreads();
        f16x8 a[4];
        #pragma unroll
        for (int rt = 0; rt < 4; ++rt)
            a[rt] = *(const f16x8*)&tb[(rt * 16 + m) * LD + quad * 8];
        #pragma unroll
        for (int ct = 0; ct < NCT; ++ct) {
            #pragma unroll
            for (int rt = 0; rt < 4; ++rt)
                acc[rt][ct] = __builtin_amdgcn_mfma_f32_16x16x32_f16(a[rt], bb[ct], acc[rt][ct], 0, 0, 0);
        }
        #pragma unroll
        for (int ct = 0; ct < NCT; ++ct)
            bb[ct] = bn[ct];
    }
    #pragma unroll
    for (int ct = 0; ct < NCT; ++ct) {
        float vmax = -3.4e38f;
        #pragma unroll
        for (int rt = 0; rt < 4; ++rt) {
            vmax = fmaxf(vmax, acc[rt][ct][0]);
            vmax = fmaxf(vmax, acc[rt][ct][1]);
            vmax = fmaxf(vmax, acc[rt][ct][2]);
            vmax = fmaxf(vmax, acc[rt][ct][3]);
        }
        vmax = fmaxf(vmax, __shfl_xor(vmax, 16));
        vmax = fmaxf(vmax, __shfl_xor(vmax, 32));
        if (quad == 0) {
            int col = cw + ct * 16 + m;
            Y[(size_t)i * C + col] = vmax + b2[col];
        }
    }
}

// ---------------- Classifier: [N,512] @ [512,14] + b ----------------
__global__ __launch_bounds__(256) void cls_kernel(const float* __restrict__ h, const float* __restrict__ w,
                                                  const float* __restrict__ bias, float* __restrict__ out) {
    __shared__ float wl[512 * 14];
    int tid = threadIdx.x;
    for (int idx = tid; idx < 512 * 14; idx += 256) wl[idx] = w[idx];
    __syncthreads();
    if (tid < 224) {
        int nl = tid / 14, c = tid - nl * 14;
        int n = blockIdx.x * 16 + nl;
        float acc = bias[c];
        const float* hr = h + (size_t)n * 512;
        for (int k = 0; k < 512; ++k)
            acc += hr[k] * wl[k * 14 + c];
        out[(size_t)n * 14 + c] = acc;
    }
}

extern "C" void kernel_launch(void* const* d_in, const int* in_sizes, int n_in,
                              void* d_out, int out_size, void* d_ws, size_t ws_size,
                              hipStream_t stream) {
    const float* pos = (const float*)d_in[0];
    const float* gnw[6]; const float* gnb[6]; const float* gnms[6];
    for (int i = 0; i < 6; ++i) {
        gnw[i]  = (const float*)d_in[2 + 3 * i];
        gnb[i]  = (const float*)d_in[3 + 3 * i];
        gnms[i] = (const float*)d_in[4 + 3 * i];
    }
    const float* cw1[5]; const float* cb1[5]; const float* cw2[5]; const float* cb2[5];
    for (int i = 0; i < 5; ++i) {
        cw1[i] = (const float*)d_in[20 + 4 * i];
        cb1[i] = (const float*)d_in[21 + 4 * i];
        cw2[i] = (const float*)d_in[22 + 4 * i];
        cb2[i] = (const float*)d_in[23 + 4 * i];
    }
    const float* clsw = (const float*)d_in[40];
    const float* clsb = (const float*)d_in[41];
    float* out = (float*)d_out;

    char* ws = (char*)d_ws;
    int* knn            = (int*)(ws + 0);                 // 1 MB
    float* U            = (float*)(ws + 1048576);         // 8 MB
    float* P            = (float*)(ws + 9437184);         // 8 MB
    float* h            = (float*)(ws + 17825792);        // 8 MB
    float* y            = (float*)(ws + 26214400);        // 8 MB
    unsigned short* w2t = (unsigned short*)(ws + 34635776); // 512 KB

    knn_kernel<<<N_NODES, 512, 0, stream>>>(pos, knn);

    // gn1 on pos -> h [N,3] (no relu)
    gn_fused<<<dim3(1, NGRAPH), 256, 0, stream>>>(pos, gnms[0], gnw[0], gnb[0], 3, h, 0);

    // Layer 1: CIN=3, C=64
    node_kernel<3, 64><<<N_NODES / 16, 64, 0, stream>>>(h, pos, cw1[0], cb1[0], U, P);
    w2tt_kernel<<<(64 * 64 + 255) / 256, 256, 0, stream>>>(cw2[0], w2t, 64);
    edge_kernel<64, 4><<<N_NODES, 256, 0, stream>>>(U, P, knn, w2t, cb2[0], y);
    gn_fused<<<dim3(1, NGRAPH), 256, 0, stream>>>(y, gnms[1], gnw[1], gnb[1], 64, h, 1);

    // Layer 2: CIN=64, C=128
    node_kernel<64, 128><<<N_NODES / 16, 128, 0, stream>>>(h, pos, cw1[1], cb1[1], U, P);
    w2tt_kernel<<<(128 * 128 + 255) / 256, 256, 0, stream>>>(cw2[1], w2t, 128);
    edge_kernel<128, 8><<<N_NODES, 512, 0, stream>>>(U, P, knn, w2t, cb2[1], y);
    gn_fused<<<dim3(2, NGRAPH), 256, 0, stream>>>(y, gnms[2], gnw[2], gnb[2], 128, h, 1);

    // Layer 3: CIN=128, C=256
    node_kernel<128, 256><<<N_NODES / 16, 256, 0, stream>>>(h, pos, cw1[2], cb1[2], U, P);
    w2tt_kernel<<<(256 * 256 + 255) / 256, 256, 0, stream>>>(cw2[2], w2t, 256);
    edge_kernel<256, 8><<<N_NODES, 512, 0, stream>>>(U, P, knn, w2t, cb2[2], y);
    gn_fused<<<dim3(4, NGRAPH), 256, 0, stream>>>(y, gnms[3], gnw[3], gnb[3], 256, h, 1);

    // Layer 4: CIN=256, C=512
    node_kernel<256, 512><<<N_NODES / 16, 512, 0, stream>>>(h, pos, cw1[3], cb1[3], U, P);
    w2tt_kernel<<<(512 * 512 + 255) / 256, 256, 0, stream>>>(cw2[3], w2t, 512);
    edge_kernel<512, 8><<<N_NODES, 512, 0, stream>>>(U, P, knn, w2t, cb2[3], y);
    gn_fused<<<dim3(8, NGRAPH), 256, 0, stream>>>(y, gnms[4], gnw[4], gnb[4], 512, h, 1);

    // Layer 5: CIN=512, C=512
    node_kernel<512, 512><<<N_NODES / 16, 512, 0, stream>>>(h, pos, cw1[4], cb1[4], U, P);
    w2tt_kernel<<<(512 * 512 + 255) / 256, 256, 0, stream>>>(cw2[4], w2t, 512);
    edge_kernel<512, 8><<<N_NODES, 512, 0, stream>>>(U, P, knn, w2t, cb2[4], y);
    gn_fused<<<dim3(8, NGRAPH), 256, 0, stream>>>(y, gnms[5], gnw[5], gnb[5], 512, h, 1);

    cls_kernel<<<N_NODES / 16, 256, 0, stream>>>(h, clsw, clsb, out);
}

// Round 9
// 976.451 us; speedup vs baseline: 1.0857x; 1.0857x over previous
//
#include <hip/hip_runtime.h>
#include <stdint.h>

#define N_NODES 4096
#define NGRAPH 8
#define NPTS 512
#define KNN 64
#define EPSN 1e-5f

typedef _Float16 f16x8 __attribute__((ext_vector_type(8)));
typedef float f32x4 __attribute__((ext_vector_type(4)));

__device__ __forceinline__ unsigned short f2h(float f) {
    _Float16 h = (_Float16)f;   // RNE, v_cvt_f16_f32
    union { _Float16 h; unsigned short u; } cv; cv.h = h;
    return cv.u;
}

// ---------------- kNN: one block per dst point, bitonic sort of 512 (d2,idx) keys ----------------
__global__ __launch_bounds__(512) void knn_kernel(const float* __restrict__ pos, int* __restrict__ knn_out) {
#pragma clang fp contract(off)
    __shared__ float px[NPTS], py[NPTS], pz[NPTS];
    __shared__ unsigned long long keys[NPTS];
    int b = blockIdx.x >> 9;
    int il = blockIdx.x & (NPTS - 1);
    int tid = threadIdx.x;
    {
        int base = (b * NPTS + tid) * 3;
        px[tid] = pos[base]; py[tid] = pos[base + 1]; pz[tid] = pos[base + 2];
    }
    __syncthreads();
    float xi = px[il], yi = py[il], zi = pz[il];
    {
        float dx = px[tid] - xi, dy = py[tid] - yi, dz = pz[tid] - zi;
        float d2 = dx * dx;
        d2 = d2 + dy * dy;
        d2 = d2 + dz * dz;
        keys[tid] = (((unsigned long long)__float_as_uint(d2)) << 32) | (unsigned)tid;
    }
    for (int k2 = 2; k2 <= NPTS; k2 <<= 1) {
        for (int j = k2 >> 1; j > 0; j >>= 1) {
            __syncthreads();
            int ixj = tid ^ j;
            if (ixj > tid) {
                unsigned long long a = keys[tid], c = keys[ixj];
                bool up = ((tid & k2) == 0);
                if ((a > c) == up) { keys[tid] = c; keys[ixj] = a; }
            }
        }
    }
    __syncthreads();
    if (tid < KNN) {
        int j = (int)(keys[tid] & 0xffffffffu);
        knn_out[(b * NPTS + il) * KNN + tid] = b * NPTS + j;
    }
}

// ---------------- GraphNorm fused: stats + apply (+optional relu) ----------------
__global__ __launch_bounds__(256) void gn_fused(const float* __restrict__ x, const float* __restrict__ ms,
                                                const float* __restrict__ w, const float* __restrict__ bn,
                                                int C, float* __restrict__ out, int relu) {
    __shared__ float r1[4][64], r2[4][64];
    __shared__ float As[64], Ss[64];
    int b = blockIdx.y;
    int cl = threadIdx.x & 63;
    int c = blockIdx.x * 64 + cl;
    int part = threadIdx.x >> 6;
    float s1 = 0.f, s2 = 0.f;
    if (c < C) {
        for (int n = part; n < NPTS; n += 4) {
            float v = x[(size_t)(b * NPTS + n) * C + c];
            s1 += v; s2 += v * v;
        }
    }
    r1[part][cl] = s1;
    r2[part][cl] = s2;
    __syncthreads();
    if (part == 0 && c < C) {
        s1 = r1[0][cl] + r1[1][cl] + r1[2][cl] + r1[3][cl];
        s2 = r2[0][cl] + r2[1][cl] + r2[2][cl] + r2[3][cl];
        float mean = s1 * (1.f / NPTS);
        float ex2 = s2 * (1.f / NPTS);
        float a = mean * ms[c];
        float var = ex2 - 2.f * a * mean + a * a;   // E[(x - mean*ms)^2]
        As[cl] = a;
        Ss[cl] = w[c] / sqrtf(var + EPSN);
    }
    __syncthreads();
    if (c < C) {
        float a = As[cl], sf = Ss[cl], bb = bn[c];
        for (int n = part; n < NPTS; n += 4) {
            size_t idx = (size_t)(b * NPTS + n) * C + c;
            float v = (x[idx] - a) * sf + bb;
            if (relu) v = fmaxf(v, 0.f);
            out[idx] = v;
        }
    }
}

// ---------------- Per-node MLP1 v2: each block computes 16 rows x ALL C cols ----------------
template<int CIN, int C>
__global__ __launch_bounds__(C) void node_kernel(const float* __restrict__ h, const float* __restrict__ pos,
                                                 const float* __restrict__ w1, const float* __restrict__ b1,
                                                 float* __restrict__ U, float* __restrict__ P) {
    constexpr int ROWS = 16;
    constexpr int KC = 64;
    constexpr int LDH = KC + 4;
    __shared__ float hs[ROWS][LDH];   // 4352 B
    const int c = threadIdx.x;
    const int n0 = blockIdx.x * ROWS;
    float acc[ROWS];
    #pragma unroll
    for (int r = 0; r < ROWS; ++r) acc[r] = 0.f;
    constexpr int NCHUNK = (CIN + KC - 1) / KC;
    #pragma unroll 1
    for (int s = 0; s < NCHUNK; ++s) {
        const int k0 = s * KC;
        const int kc = (CIN - k0 < KC) ? (CIN - k0) : KC;
        __syncthreads();
        for (int idx = c; idx < ROWS * kc; idx += C) {
            int r = idx / kc, k = idx - r * kc;
            hs[r][k] = h[(size_t)(n0 + r) * CIN + k0 + k];
        }
        __syncthreads();
        int k = 0;
        for (; k + 4 <= kc; k += 4) {
            float w0 = w1[(size_t)(k0 + k) * C + c];
            float w1v = w1[(size_t)(k0 + k + 1) * C + c];
            float w2v = w1[(size_t)(k0 + k + 2) * C + c];
            float w3v = w1[(size_t)(k0 + k + 3) * C + c];
            #pragma unroll
            for (int r = 0; r < ROWS; ++r) {
                f32x4 hv = *(const f32x4*)&hs[r][k];
                acc[r] = fmaf(hv[0], w0, acc[r]);
                acc[r] = fmaf(hv[1], w1v, acc[r]);
                acc[r] = fmaf(hv[2], w2v, acc[r]);
                acc[r] = fmaf(hv[3], w3v, acc[r]);
            }
        }
        for (; k < kc; ++k) {
            float wv = w1[(size_t)(k0 + k) * C + c];
            #pragma unroll
            for (int r = 0; r < ROWS; ++r)
                acc[r] = fmaf(hs[r][k], wv, acc[r]);
        }
    }
    float pacc[ROWS];
    #pragma unroll
    for (int r = 0; r < ROWS; ++r) pacc[r] = 0.f;
    #pragma unroll
    for (int e = 0; e < 3; ++e) {
        float wv = w1[(size_t)(CIN + e) * C + c];
        #pragma unroll
        for (int r = 0; r < ROWS; ++r)
            pacc[r] = fmaf(pos[(n0 + r) * 3 + e], wv, pacc[r]);
    }
    float bv = b1[c];
    #pragma unroll
    for (int r = 0; r < ROWS; ++r) {
        U[(size_t)(n0 + r) * C + c] = acc[r] + pacc[r] + bv;
        P[(size_t)(n0 + r) * C + c] = pacc[r];
    }
}

// ---------------- w2 (C x C fp32, [k][n]) -> blocked fp16 layout ----------------
// dst[(ctg*(C/32)+s32)*512 + quad*128 + m*8 + j]  where n = ctg*16+m, k = s32*32+quad*8+j
__global__ void w2tt_kernel(const float* __restrict__ w2, unsigned short* __restrict__ w2t, int C) {
    int idx = blockIdx.x * 256 + threadIdx.x;
    if (idx >= C * C) return;
    int k = idx / C, n = idx % C;
    int dst = ((n >> 4) * (C / 32) + (k >> 5)) * 512 + ((k >> 3) & 3) * 128 + (n & 15) * 8 + (k & 7);
    w2t[dst] = f2h(w2[idx]);
}

// ---------------- Edge MLP2 + scatter-max ----------------
// One block per dst node (XCD-graph-swizzled). W waves; wave w owns cols [w*NCT*16,(w+1)*NCT*16).
// BK=32 per barrier iter; A-prefetch (U/P regs) + LDS dbuf. B loaded in MFMA phase (R6 cadence).
template<int C, int W>
__global__ __launch_bounds__(W * 64, 4) void edge_kernel(const float* __restrict__ U, const float* __restrict__ P,
                                                         const int* __restrict__ knn, const unsigned short* __restrict__ w2t,
                                                         const float* __restrict__ b2, float* __restrict__ Y) {
    constexpr int NCT = C / (W * 16);    // col tiles per wave
    constexpr int EPT = 32 / W;          // staging cols per thread (8 or 4)
    constexpr int S = C / 32;            // barrier iterations (one k32 each)
    constexpr int LD = 40;               // LDS row stride (halves)
    __shared__ unsigned short Tb[2][64 * LD];
    __shared__ int jn[64];
    const int bid = blockIdx.x;
    const int i = ((bid & 7) << 9) | (bid >> 3);   // XCD = bid%8 = graph(i): gather stays in one L2
    const int tid = threadIdx.x;
    const int wave = tid >> 6, lane = tid & 63, m = lane & 15, quad = lane >> 4;
    const int cw = wave * (NCT * 16);
    if (tid < 64) jn[tid] = knn[(size_t)i * KNN + tid];
    f32x4 acc[4][NCT];
    f32x4 zero = {0.f, 0.f, 0.f, 0.f};
    #pragma unroll
    for (int rt = 0; rt < 4; ++rt)
        #pragma unroll
        for (int ct = 0; ct < NCT; ++ct)
            acc[rt][ct] = zero;
    const int rr = tid / W;              // staging row 0..63
    const int c0 = (tid % W) * EPT;      // staging col base within k32 window
    __syncthreads();                     // jn visible
    const float* upr = U + (size_t)jn[rr] * C + c0;
    const float* ppr = P + (size_t)i * C + c0;
    float4 uf[EPT / 4], pf[EPT / 4];
    #pragma unroll
    for (int g = 0; g < EPT / 4; ++g) {
        uf[g] = *(const float4*)(upr + g * 4);
        pf[g] = *(const float4*)(ppr + g * 4);
    }
    #pragma unroll 2
    for (int s = 0; s < S; ++s) {
        unsigned short* tb = Tb[s & 1];
        if constexpr (EPT == 8) {
            uint4 pk;
            pk.x = (unsigned)f2h(fmaxf(uf[0].x - pf[0].x, 0.f)) | ((unsigned)f2h(fmaxf(uf[0].y - pf[0].y, 0.f)) << 16);
            pk.y = (unsigned)f2h(fmaxf(uf[0].z - pf[0].z, 0.f)) | ((unsigned)f2h(fmaxf(uf[0].w - pf[0].w, 0.f)) << 16);
            pk.z = (unsigned)f2h(fmaxf(uf[1].x - pf[1].x, 0.f)) | ((unsigned)f2h(fmaxf(uf[1].y - pf[1].y, 0.f)) << 16);
            pk.w = (unsigned)f2h(fmaxf(uf[1].z - pf[1].z, 0.f)) | ((unsigned)f2h(fmaxf(uf[1].w - pf[1].w, 0.f)) << 16);
            *(uint4*)&tb[rr * LD + c0] = pk;
        } else {
            uint2 pk;
            pk.x = (unsigned)f2h(fmaxf(uf[0].x - pf[0].x, 0.f)) | ((unsigned)f2h(fmaxf(uf[0].y - pf[0].y, 0.f)) << 16);
            pk.y = (unsigned)f2h(fmaxf(uf[0].z - pf[0].z, 0.f)) | ((unsigned)f2h(fmaxf(uf[0].w - pf[0].w, 0.f)) << 16);
            *(uint2*)&tb[rr * LD + c0] = pk;
        }
        if (s + 1 < S) {                 // A-prefetch next k32 window
            #pragma unroll
            for (int g = 0; g < EPT / 4; ++g) {
                uf[g] = *(const float4*)(upr + (s + 1) * 32 + g * 4);
                pf[g] = *(const float4*)(ppr + (s + 1) * 32 + g * 4);
            }
        }
        __syncthreads();
        f16x8 a[4];
        #pragma unroll
        for (int rt = 0; rt < 4; ++rt)
            a[rt] = *(const f16x8*)&tb[(rt * 16 + m) * LD + quad * 8];
        #pragma unroll
        for (int ct = 0; ct < NCT; ++ct) {
            const f16x8 bb = *(const f16x8*)(w2t +
                (size_t)(((cw >> 4) + ct) * S + s) * 512 + quad * 128 + m * 8);
            #pragma unroll
            for (int rt = 0; rt < 4; ++rt)
                acc[rt][ct] = __builtin_amdgcn_mfma_f32_16x16x32_f16(a[rt], bb, acc[rt][ct], 0, 0, 0);
        }
    }
    #pragma unroll
    for (int ct = 0; ct < NCT; ++ct) {
        float vmax = -3.4e38f;
        #pragma unroll
        for (int rt = 0; rt < 4; ++rt) {
            vmax = fmaxf(vmax, acc[rt][ct][0]);
            vmax = fmaxf(vmax, acc[rt][ct][1]);
            vmax = fmaxf(vmax, acc[rt][ct][2]);
            vmax = fmaxf(vmax, acc[rt][ct][3]);
        }
        vmax = fmaxf(vmax, __shfl_xor(vmax, 16));
        vmax = fmaxf(vmax, __shfl_xor(vmax, 32));
        if (quad == 0) {
            int col = cw + ct * 16 + m;
            Y[(size_t)i * C + col] = vmax + b2[col];
        }
    }
}

// ---------------- Classifier: [N,512] @ [512,14] + b ----------------
__global__ __launch_bounds__(256) void cls_kernel(const float* __restrict__ h, const float* __restrict__ w,
                                                  const float* __restrict__ bias, float* __restrict__ out) {
    __shared__ float wl[512 * 14];
    int tid = threadIdx.x;
    for (int idx = tid; idx < 512 * 14; idx += 256) wl[idx] = w[idx];
    __syncthreads();
    if (tid < 224) {
        int nl = tid / 14, c = tid - nl * 14;
        int n = blockIdx.x * 16 + nl;
        float acc = bias[c];
        const float* hr = h + (size_t)n * 512;
        for (int k = 0; k < 512; ++k)
            acc += hr[k] * wl[k * 14 + c];
        out[(size_t)n * 14 + c] = acc;
    }
}

extern "C" void kernel_launch(void* const* d_in, const int* in_sizes, int n_in,
                              void* d_out, int out_size, void* d_ws, size_t ws_size,
                              hipStream_t stream) {
    const float* pos = (const float*)d_in[0];
    const float* gnw[6]; const float* gnb[6]; const float* gnms[6];
    for (int i = 0; i < 6; ++i) {
        gnw[i]  = (const float*)d_in[2 + 3 * i];
        gnb[i]  = (const float*)d_in[3 + 3 * i];
        gnms[i] = (const float*)d_in[4 + 3 * i];
    }
    const float* cw1[5]; const float* cb1[5]; const float* cw2[5]; const float* cb2[5];
    for (int i = 0; i < 5; ++i) {
        cw1[i] = (const float*)d_in[20 + 4 * i];
        cb1[i] = (const float*)d_in[21 + 4 * i];
        cw2[i] = (const float*)d_in[22 + 4 * i];
        cb2[i] = (const float*)d_in[23 + 4 * i];
    }
    const float* clsw = (const float*)d_in[40];
    const float* clsb = (const float*)d_in[41];
    float* out = (float*)d_out;

    char* ws = (char*)d_ws;
    int* knn            = (int*)(ws + 0);                 // 1 MB
    float* U            = (float*)(ws + 1048576);         // 8 MB
    float* P            = (float*)(ws + 9437184);         // 8 MB
    float* h            = (float*)(ws + 17825792);        // 8 MB
    float* y            = (float*)(ws + 26214400);        // 8 MB
    unsigned short* w2t = (unsigned short*)(ws + 34635776); // 512 KB

    knn_kernel<<<N_NODES, 512, 0, stream>>>(pos, knn);

    // gn1 on pos -> h [N,3] (no relu)
    gn_fused<<<dim3(1, NGRAPH), 256, 0, stream>>>(pos, gnms[0], gnw[0], gnb[0], 3, h, 0);

    // Layer 1: CIN=3, C=64
    node_kernel<3, 64><<<N_NODES / 16, 64, 0, stream>>>(h, pos, cw1[0], cb1[0], U, P);
    w2tt_kernel<<<(64 * 64 + 255) / 256, 256, 0, stream>>>(cw2[0], w2t, 64);
    edge_kernel<64, 4><<<N_NODES, 256, 0, stream>>>(U, P, knn, w2t, cb2[0], y);
    gn_fused<<<dim3(1, NGRAPH), 256, 0, stream>>>(y, gnms[1], gnw[1], gnb[1], 64, h, 1);

    // Layer 2: CIN=64, C=128
    node_kernel<64, 128><<<N_NODES / 16, 128, 0, stream>>>(h, pos, cw1[1], cb1[1], U, P);
    w2tt_kernel<<<(128 * 128 + 255) / 256, 256, 0, stream>>>(cw2[1], w2t, 128);
    edge_kernel<128, 8><<<N_NODES, 512, 0, stream>>>(U, P, knn, w2t, cb2[1], y);
    gn_fused<<<dim3(2, NGRAPH), 256, 0, stream>>>(y, gnms[2], gnw[2], gnb[2], 128, h, 1);

    // Layer 3: CIN=128, C=256
    node_kernel<128, 256><<<N_NODES / 16, 256, 0, stream>>>(h, pos, cw1[2], cb1[2], U, P);
    w2tt_kernel<<<(256 * 256 + 255) / 256, 256, 0, stream>>>(cw2[2], w2t, 256);
    edge_kernel<256, 8><<<N_NODES, 512, 0, stream>>>(U, P, knn, w2t, cb2[2], y);
    gn_fused<<<dim3(4, NGRAPH), 256, 0, stream>>>(y, gnms[3], gnw[3], gnb[3], 256, h, 1);

    // Layer 4: CIN=256, C=512
    node_kernel<256, 512><<<N_NODES / 16, 512, 0, stream>>>(h, pos, cw1[3], cb1[3], U, P);
    w2tt_kernel<<<(512 * 512 + 255) / 256, 256, 0, stream>>>(cw2[3], w2t, 512);
    edge_kernel<512, 8><<<N_NODES, 512, 0, stream>>>(U, P, knn, w2t, cb2[3], y);
    gn_fused<<<dim3(8, NGRAPH), 256, 0, stream>>>(y, gnms[4], gnw[4], gnb[4], 512, h, 1);

    // Layer 5: CIN=512, C=512
    node_kernel<512, 512><<<N_NODES / 16, 512, 0, stream>>>(h, pos, cw1[4], cb1[4], U, P);
    w2tt_kernel<<<(512 * 512 + 255) / 256, 256, 0, stream>>>(cw2[4], w2t, 512);
    edge_kernel<512, 8><<<N_NODES, 512, 0, stream>>>(U, P, knn, w2t, cb2[4], y);
    gn_fused<<<dim3(8, NGRAPH), 256, 0, stream>>>(y, gnms[5], gnw[5], gnb[5], 512, h, 1);

    cls_kernel<<<N_NODES / 16, 256, 0, stream>>>(h, clsw, clsb, out);
}